// Round 1
// baseline (4434.737 us; speedup 1.0000x reference)
//
#include <hip/hip_runtime.h>
#include <hip/hip_cooperative_groups.h>
#include <math.h>

namespace cg = cooperative_groups;

#define B_     128
#define L_     100
#define HID_   256
#define IND_   160
#define NCLASS 19
#define CAPD   16
#define NI     1600      // L_ * NUM_CAPS
#define OD     304       // NCLASS * CAPD
#define ENTITY 68

// ---------------------------------------------------------------------------
// Phase 0: embedding gather -> emb [b*L_+t][160]
// ---------------------------------------------------------------------------
__global__ void emb_gather(const int* __restrict__ word, const int* __restrict__ tag,
                           const int* __restrict__ pos1, const int* __restrict__ pos2,
                           const float* __restrict__ we, const float* __restrict__ te,
                           const float* __restrict__ p1e, const float* __restrict__ p2e,
                           float* __restrict__ emb)
{
    int idx = blockIdx.x * 256 + threadIdx.x;          // exactly B_*L_*IND_ threads
    int bt = idx / IND_;
    int k  = idx - bt * IND_;
    float v;
    if (k < 100)      v = we[word[bt] * 100 + k];
    else if (k < 120) v = te[tag[bt] * 20 + (k - 100)];
    else if (k < 140) v = p1e[pos1[bt] * 20 + (k - 120)];
    else              v = p2e[pos2[bt] * 20 + (k - 140)];
    emb[idx] = v;
}

// ---------------------------------------------------------------------------
// Phase 1: input-gate GEMM  xg[dir][t][gj(1024)][b(128)] = emb @ w_ih^T + b_ih + b_hh
// block: (gj-tile 0..7, t 0..99, dir 0..1), 256 threads, 128x128 tile, K=160
// ---------------------------------------------------------------------------
__global__ void __launch_bounds__(256) gemm_xg(
    const float* __restrict__ emb,
    const float* __restrict__ wihf, const float* __restrict__ bihf, const float* __restrict__ bhhf,
    const float* __restrict__ wihb, const float* __restrict__ bihb, const float* __restrict__ bhhb,
    float* __restrict__ xg)
{
    int gt  = blockIdx.x;
    int t   = blockIdx.y;
    int dir = blockIdx.z;
    const float* w  = dir ? wihb : wihf;
    const float* bi = dir ? bihb : bihf;
    const float* bh = dir ? bhhb : bhhf;
    int gj0 = gt * 128;

    __shared__ float wsh[32][132];   // [k][gj], padded
    __shared__ float esh[32][132];   // [k][b],  padded

    int tid = threadIdx.x;
    int tx = tid & 15, ty = tid >> 4;

    float acc[8][8];
    #pragma unroll
    for (int i = 0; i < 8; ++i)
        #pragma unroll
        for (int j = 0; j < 8; ++j) acc[i][j] = 0.f;

    for (int k0 = 0; k0 < IND_; k0 += 32) {
        __syncthreads();
        #pragma unroll
        for (int m = 0; m < 16; ++m) {
            int e = m * 256 + tid;        // 0..4095
            int k = e & 31, g = e >> 5;   // g: row (gj or b)
            wsh[k][g] = w[(gj0 + g) * IND_ + k0 + k];
            esh[k][g] = emb[(g * L_ + t) * IND_ + k0 + k];
        }
        __syncthreads();
        #pragma unroll
        for (int k = 0; k < 32; ++k) {
            float wv[8], ev[8];
            #pragma unroll
            for (int q = 0; q < 8; ++q) wv[q] = wsh[k][ty * 8 + q];
            #pragma unroll
            for (int q = 0; q < 8; ++q) ev[q] = esh[k][tx * 8 + q];
            #pragma unroll
            for (int i = 0; i < 8; ++i)
                #pragma unroll
                for (int j = 0; j < 8; ++j) acc[i][j] = fmaf(wv[i], ev[j], acc[i][j]);
        }
    }
    #pragma unroll
    for (int i = 0; i < 8; ++i) {
        int gj = gj0 + ty * 8 + i;
        float bias = bi[gj] + bh[gj];
        #pragma unroll
        for (int j = 0; j < 8; ++j) {
            int b = tx * 8 + j;
            xg[(((size_t)dir * L_ + t) * 1024 + gj) * B_ + b] = acc[i][j] + bias;
        }
    }
}

// ---------------------------------------------------------------------------
// Phase 2: BiLSTM scan (cooperative, 256 blocks x 256 threads, grid sync per step)
// thread <-> (dir, b, j); cell state c lives in a register the whole scan.
// h stored transposed [dir][k][b] so reads coalesce over b; w_hh addresses are
// wave-uniform -> scalar loads.
// ---------------------------------------------------------------------------
__global__ void __launch_bounds__(256, 1) lstm_scan(
    const float* __restrict__ xg, const float* __restrict__ whhf,
    const float* __restrict__ whhb, float* __restrict__ hbuf, float* __restrict__ x)
{
    cg::grid_group grid = cg::this_grid();
    int bi  = blockIdx.x;
    int dir = bi >> 7;
    int j0  = (bi & 127) * 2;
    int tid = threadIdx.x;
    int b   = tid & 127;
    int jj  = __builtin_amdgcn_readfirstlane((tid >> 7) & 1);
    int j   = j0 + jj;

    const float* whh = dir ? whhb : whhf;
    const float* wr0 = whh + (0 * HID_ + j) * HID_;
    const float* wr1 = whh + (1 * HID_ + j) * HID_;
    const float* wr2 = whh + (2 * HID_ + j) * HID_;
    const float* wr3 = whh + (3 * HID_ + j) * HID_;
    const float* xgd = xg + (size_t)dir * L_ * 1024 * B_;

    float c = 0.f;
    hbuf[((0 * 2 + dir) * HID_ + j) * B_ + b] = 0.f;   // phase-0 h = 0
    grid.sync();

    for (int t = 0; t < L_; ++t) {
        int slot = dir ? (L_ - 1 - t) : t;
        const float* hp = hbuf + (size_t)((t & 1) * 2 + dir) * HID_ * B_;
        float*       hn = hbuf + (size_t)((((t + 1) & 1)) * 2 + dir) * HID_ * B_;
        const float* xp = xgd + (size_t)slot * 1024 * B_ + j * B_ + b;
        float a0 = xp[0 * HID_ * B_];
        float a1 = xp[1 * HID_ * B_];
        float a2 = xp[2 * HID_ * B_];
        float a3 = xp[3 * HID_ * B_];
        #pragma unroll 8
        for (int k = 0; k < HID_; ++k) {
            float hk = hp[k * B_ + b];
            a0 = fmaf(wr0[k], hk, a0);
            a1 = fmaf(wr1[k], hk, a1);
            a2 = fmaf(wr2[k], hk, a2);
            a3 = fmaf(wr3[k], hk, a3);
        }
        float ig = 1.f / (1.f + expf(-a0));
        float fg = 1.f / (1.f + expf(-a1));
        float gg = tanhf(a2);
        float og = 1.f / (1.f + expf(-a3));
        c = fg * c + ig * gg;
        float h = og * tanhf(c);
        hn[j * B_ + b] = h;
        float* xo = x + ((size_t)slot * HID_ + j) * B_ + b;
        if (t < 50) *xo = h; else *xo += h;   // first writer stores, second adds
        grid.sync();
    }
}

// ---------------------------------------------------------------------------
// Phase 3: entity features, attention, primary capsules
// ---------------------------------------------------------------------------
__global__ void find_entity(const int* __restrict__ pos1, const int* __restrict__ pos2,
                            int* __restrict__ e)
{
    int b = threadIdx.x;
    int e1 = 0, e2 = 0;
    for (int l = L_ - 1; l >= 0; --l) if (pos1[b * L_ + l] == ENTITY) e1 = l;
    for (int l = L_ - 1; l >= 0; --l) if (pos2[b * L_ + l] == ENTITY) e2 = l;
    e[b] = e1; e[B_ + b] = e2;
}

__global__ void compute_he(const float* __restrict__ x, const int* __restrict__ e,
                           float* __restrict__ he)
{
    int j = blockIdx.x, b = threadIdx.x;
    int e1 = e[b], e2 = e[B_ + b];
    he[j * B_ + b] = x[((size_t)e1 * HID_ + j) * B_ + b] + x[((size_t)e2 * HID_ + j) * B_ + b];
}

__global__ void att_logits(const float* __restrict__ x, const float* __restrict__ he,
                           float* __restrict__ logits)
{
    int l = blockIdx.x, b = threadIdx.x;
    float acc = 0.f;
    for (int j = 0; j < HID_; ++j)
        acc = fmaf(x[((size_t)l * HID_ + j) * B_ + b], he[j * B_ + b], acc);
    logits[l * B_ + b] = acc;
}

__global__ void att_softmax(const float* __restrict__ logits, float* __restrict__ att)
{
    int b = threadIdx.x;
    float m = -1e30f;
    for (int l = 0; l < L_; ++l) m = fmaxf(m, logits[l * B_ + b]);
    float s = 0.f;
    for (int l = 0; l < L_; ++l) s += expf(logits[l * B_ + b] - m);
    float inv = 1.f / s;
    for (int l = 0; l < L_; ++l) att[l * B_ + b] = expf(logits[l * B_ + b] - m) * inv;
}

// primary capsules: u[i][b][c], squashed
__global__ void u_squash(const float* __restrict__ x, float* __restrict__ u)
{
    int i = blockIdx.x, b = threadIdx.x;
    int l = i >> 4, cap = i & 15;
    float vals[16]; float n2 = 0.f;
    #pragma unroll
    for (int c2 = 0; c2 < 16; ++c2) {
        float v = x[((size_t)l * HID_ + cap * 16 + c2) * B_ + b];
        vals[c2] = v; n2 = fmaf(v, v, n2);
    }
    float f = (n2 / (1.f + n2)) / sqrtf(n2 + 1e-9f);
    #pragma unroll
    for (int c2 = 0; c2 < 16; ++c2)
        u[((size_t)i * B_ + b) * 16 + c2] = vals[c2] * f;
}

// ---------------------------------------------------------------------------
// Phase 4: routing
// ---------------------------------------------------------------------------
__global__ void bb_init(const float* __restrict__ br, float* __restrict__ bb)
{
    int idx = blockIdx.x * 256 + threadIdx.x;   // exactly B_*NI*NCLASS threads
    bb[idx] = br[idx % (NI * NCLASS)];
}

// s-pass: per block (i-chunk of 16, b-tile of 16): fused softmax(bb)*alpha, then
// partial_s[ic][b][od] = sum_i c_bio * (sum_c u_bic W_icod)
__global__ void __launch_bounds__(320) s_pass(
    const float* __restrict__ u, const float* __restrict__ W,
    const float* __restrict__ bb, const float* __restrict__ att,
    float* __restrict__ partial)
{
    int ic = blockIdx.x, bt = blockIdx.y;
    int i0 = ic * 16, b0 = bt * 16;
    __shared__ float C[16][16][20];   // [bl][il][o], padded
    int tid = threadIdx.x;
    if (tid < 256) {
        int bl = tid >> 4, il = tid & 15;
        int b = b0 + bl, i = i0 + il;
        const float* bbp = bb + ((size_t)b * NI + i) * NCLASS;
        float m = bbp[0];
        #pragma unroll
        for (int o = 1; o < NCLASS; ++o) m = fmaxf(m, bbp[o]);
        float s = 0.f; float e[NCLASS];
        #pragma unroll
        for (int o = 0; o < NCLASS; ++o) { e[o] = expf(bbp[o] - m); s += e[o]; }
        float al = att[(i >> 4) * B_ + b] / s;
        #pragma unroll
        for (int o = 0; o < NCLASS; ++o) C[bl][il][o] = e[o] * al;
    }
    __syncthreads();
    if (tid >= OD) return;
    int od = tid, o = od >> 4;
    float acc[16];
    #pragma unroll
    for (int bl = 0; bl < 16; ++bl) acc[bl] = 0.f;
    for (int il = 0; il < 16; ++il) {
        int i = i0 + il;
        const float* wp = W + (size_t)i * 16 * OD + od;
        float w[16];
        #pragma unroll
        for (int c2 = 0; c2 < 16; ++c2) w[c2] = wp[c2 * OD];     // coalesced over od
        const float* up = u + ((size_t)i * B_ + b0) * 16;        // uniform -> s_load
        #pragma unroll
        for (int bl = 0; bl < 16; ++bl) {
            float uh = 0.f;
            #pragma unroll
            for (int c2 = 0; c2 < 16; ++c2) uh = fmaf(up[bl * 16 + c2], w[c2], uh);
            acc[bl] = fmaf(C[bl][il][o], uh, acc[bl]);
        }
    }
    #pragma unroll
    for (int bl = 0; bl < 16; ++bl)
        partial[((size_t)ic * B_ + b0 + bl) * OD + od] = acc[bl];
}

__global__ void s_reduce(const float* __restrict__ partial, float* __restrict__ s)
{
    int idx = blockIdx.x * 256 + threadIdx.x;   // exactly B_*OD threads
    int b = idx / OD, od = idx - b * OD;
    float acc = 0.f;
    for (int ic = 0; ic < 100; ++ic) acc += partial[((size_t)ic * B_ + b) * OD + od];
    s[idx] = acc;
}

__global__ void squash_v(const float* __restrict__ s, float* __restrict__ v,
                         float* __restrict__ out, int write_out)
{
    int idx = blockIdx.x * 256 + threadIdx.x;
    if (idx >= B_ * NCLASS) return;
    const float* sp = s + (size_t)idx * 16;     // b*304 + o*16 == idx*16
    float vals[16]; float n2 = 0.f;
    #pragma unroll
    for (int d = 0; d < 16; ++d) { vals[d] = sp[d]; n2 = fmaf(vals[d], vals[d], n2); }
    float f = (n2 / (1.f + n2)) / sqrtf(n2 + 1e-9f);
    float n2v = 0.f;
    #pragma unroll
    for (int d = 0; d < 16; ++d) {
        float vv = vals[d] * f;
        v[(size_t)idx * 16 + d] = vv;
        n2v = fmaf(vv, vv, n2v);
    }
    if (write_out) out[idx] = sqrtf(n2v + 1e-9f);
}

// bb-pass: bb[b][i][o] += sum_d u_hat_biod * v_bod ; u_hat recomputed like s-pass,
// d-reduction via 16-lane shuffle groups (od lanes).
__global__ void __launch_bounds__(320) bb_pass(
    const float* __restrict__ u, const float* __restrict__ W,
    const float* __restrict__ v, float* __restrict__ bb)
{
    int ic = blockIdx.x, bt = blockIdx.y;
    int i0 = ic * 16, b0 = bt * 16;
    int tid = threadIdx.x;
    if (tid >= OD) return;
    int od = tid, o = od >> 4, d = od & 15;
    float vv[16];
    #pragma unroll
    for (int bl = 0; bl < 16; ++bl) vv[bl] = v[(size_t)(b0 + bl) * OD + od];
    for (int il = 0; il < 16; ++il) {
        int i = i0 + il;
        const float* wp = W + (size_t)i * 16 * OD + od;
        float w[16];
        #pragma unroll
        for (int c2 = 0; c2 < 16; ++c2) w[c2] = wp[c2 * OD];
        const float* up = u + ((size_t)i * B_ + b0) * 16;
        #pragma unroll
        for (int bl = 0; bl < 16; ++bl) {
            float uh = 0.f;
            #pragma unroll
            for (int c2 = 0; c2 < 16; ++c2) uh = fmaf(up[bl * 16 + c2], w[c2], uh);
            float p = uh * vv[bl];
            p += __shfl_xor(p, 1);
            p += __shfl_xor(p, 2);
            p += __shfl_xor(p, 4);
            p += __shfl_xor(p, 8);
            if (d == 0) bb[((size_t)(b0 + bl) * NI + i) * NCLASS + o] += p;
        }
    }
}

// ---------------------------------------------------------------------------
extern "C" void kernel_launch(void* const* d_in, const int* in_sizes, int n_in,
                              void* d_out, int out_size, void* d_ws, size_t ws_size,
                              hipStream_t stream)
{
    (void)in_sizes; (void)n_in; (void)out_size; (void)ws_size;
    const int*   word = (const int*)d_in[0];
    const int*   tag  = (const int*)d_in[1];
    const int*   pos1 = (const int*)d_in[2];
    const int*   pos2 = (const int*)d_in[3];
    const float* we   = (const float*)d_in[4];
    const float* te   = (const float*)d_in[5];
    const float* p1e  = (const float*)d_in[6];
    const float* p2e  = (const float*)d_in[7];
    const float* wihf = (const float*)d_in[8];
    const float* whhf = (const float*)d_in[9];
    const float* bihf = (const float*)d_in[10];
    const float* bhhf = (const float*)d_in[11];
    const float* wihb = (const float*)d_in[12];
    const float* whhb = (const float*)d_in[13];
    const float* bihb = (const float*)d_in[14];
    const float* bhhb = (const float*)d_in[15];
    const float* Wc   = (const float*)d_in[16];
    const float* br   = (const float*)d_in[17];

    float* wsp    = (float*)d_ws;
    float* emb    = wsp;                       // 2,048,000
    float* xg     = wsp + 2048000;             // 26,214,400
    float* hbuf   = xg + 26214400;             // 131,072
    float* x      = hbuf + 131072;             // 3,276,800
    float* he     = x + 3276800;               // 32,768
    float* logits = he + 32768;                // 12,800
    float* att    = logits + 12800;            // 12,800
    int*   e      = (int*)(att + 12800);       // 256 ints
    // routing buffers alias the (dead-after-scan) xg region
    float* u    = xg;                          // 3,276,800
    float* bb   = xg + 3276800;                // 3,891,200
    float* part = bb + 3891200;                // 3,891,200
    float* s    = part + 3891200;              // 38,912
    float* v    = s + 38912;                   // 38,912
    float* out  = (float*)d_out;

    emb_gather<<<8000, 256, 0, stream>>>(word, tag, pos1, pos2, we, te, p1e, p2e, emb);
    gemm_xg<<<dim3(8, 100, 2), 256, 0, stream>>>(emb, wihf, bihf, bhhf, wihb, bihb, bhhb, xg);
    {
        const float* xg_c = xg;
        void* args[5] = { (void*)&xg_c, (void*)&whhf, (void*)&whhb, (void*)&hbuf, (void*)&x };
        hipLaunchCooperativeKernel(lstm_scan, dim3(256), dim3(256), args, 0, stream);
    }
    find_entity<<<1, 128, 0, stream>>>(pos1, pos2, e);
    compute_he<<<256, 128, 0, stream>>>(x, e, he);
    att_logits<<<100, 128, 0, stream>>>(x, he, logits);
    att_softmax<<<1, 128, 0, stream>>>(logits, att);
    u_squash<<<1600, 128, 0, stream>>>(x, u);
    bb_init<<<15200, 256, 0, stream>>>(br, bb);
    for (int it = 0; it < 3; ++it) {
        s_pass<<<dim3(100, 8), 320, 0, stream>>>(u, Wc, bb, att, part);
        s_reduce<<<152, 256, 0, stream>>>(part, s);
        squash_v<<<10, 256, 0, stream>>>(s, v, out, (it == 2) ? 1 : 0);
        if (it < 2) bb_pass<<<dim3(100, 8), 320, 0, stream>>>(u, Wc, v, bb);
    }
}

// Round 2
// 3913.088 us; speedup vs baseline: 1.1333x; 1.1333x over previous
//
#include <hip/hip_runtime.h>
#include <math.h>

#define B_     128
#define L_     100
#define HID_   256
#define IND_   160
#define NCLASS 19
#define CAPD   16
#define NI     1600      // L_ * NUM_CAPS
#define OD     304       // NCLASS * CAPD
#define ENTITY 68

// ---------------------------------------------------------------------------
// Phase 0: embedding gather -> emb [b*L_+t][160]
// ---------------------------------------------------------------------------
__global__ void emb_gather(const int* __restrict__ word, const int* __restrict__ tag,
                           const int* __restrict__ pos1, const int* __restrict__ pos2,
                           const float* __restrict__ we, const float* __restrict__ te,
                           const float* __restrict__ p1e, const float* __restrict__ p2e,
                           float* __restrict__ emb)
{
    int idx = blockIdx.x * 256 + threadIdx.x;          // exactly B_*L_*IND_ threads
    int bt = idx / IND_;
    int k  = idx - bt * IND_;
    float v;
    if (k < 100)      v = we[word[bt] * 100 + k];
    else if (k < 120) v = te[tag[bt] * 20 + (k - 100)];
    else if (k < 140) v = p1e[pos1[bt] * 20 + (k - 120)];
    else              v = p2e[pos2[bt] * 20 + (k - 140)];
    emb[idx] = v;
}

// ---------------------------------------------------------------------------
// Phase 1: input-gate GEMM.
// New xg layout: [dir][t][bpair(64)][gj(1024)][2]  (b = bpair*2 + c)
// so the scan's per-step gate load is a coalesced dwordx2 over lanes=j.
// ---------------------------------------------------------------------------
__global__ void __launch_bounds__(256) gemm_xg(
    const float* __restrict__ emb,
    const float* __restrict__ wihf, const float* __restrict__ bihf, const float* __restrict__ bhhf,
    const float* __restrict__ wihb, const float* __restrict__ bihb, const float* __restrict__ bhhb,
    float* __restrict__ xg)
{
    int gt  = blockIdx.x;
    int t   = blockIdx.y;
    int dir = blockIdx.z;
    const float* w  = dir ? wihb : wihf;
    const float* bi = dir ? bihb : bihf;
    const float* bh = dir ? bhhb : bhhf;
    int gj0 = gt * 128;

    __shared__ float wsh[32][132];   // [k][gj], padded
    __shared__ float esh[32][132];   // [k][b],  padded

    int tid = threadIdx.x;
    int tx = tid & 15, ty = tid >> 4;

    float acc[8][8];
    #pragma unroll
    for (int i = 0; i < 8; ++i)
        #pragma unroll
        for (int j = 0; j < 8; ++j) acc[i][j] = 0.f;

    for (int k0 = 0; k0 < IND_; k0 += 32) {
        __syncthreads();
        #pragma unroll
        for (int m = 0; m < 16; ++m) {
            int e = m * 256 + tid;        // 0..4095
            int k = e & 31, g = e >> 5;   // g: row (gj or b)
            wsh[k][g] = w[(gj0 + g) * IND_ + k0 + k];
            esh[k][g] = emb[(g * L_ + t) * IND_ + k0 + k];
        }
        __syncthreads();
        #pragma unroll
        for (int k = 0; k < 32; ++k) {
            float wv[8], ev[8];
            #pragma unroll
            for (int q = 0; q < 8; ++q) wv[q] = wsh[k][ty * 8 + q];
            #pragma unroll
            for (int q = 0; q < 8; ++q) ev[q] = esh[k][tx * 8 + q];
            #pragma unroll
            for (int i = 0; i < 8; ++i)
                #pragma unroll
                for (int j = 0; j < 8; ++j) acc[i][j] = fmaf(wv[i], ev[j], acc[i][j]);
        }
    }
    #pragma unroll
    for (int i = 0; i < 8; ++i) {
        int gj = gj0 + ty * 8 + i;
        float bias = bi[gj] + bh[gj];
        #pragma unroll
        for (int j = 0; j < 8; ++j) {
            int b = tx * 8 + j;
            xg[((((size_t)dir * L_ + t) * 64 + (b >> 1)) * 1024 + gj) * 2 + (b & 1)]
                = acc[i][j] + bias;
        }
    }
}

// ---------------------------------------------------------------------------
// Phase 2: BiLSTM scan, NO grid sync. Block = (dir, b-pair): 128 blocks x 256 thr.
// Thread j computes all 4 gates for its j, for 2 batch elements. h lives in LDS
// (__syncthreads only). Weights stream from per-XCD L2 (1 MB/dir, L2-resident).
// Model: ~3.7 us/step L2-BW-bound -> ~400 us total (was 35 us/step grid.sync).
// ---------------------------------------------------------------------------
__global__ void __launch_bounds__(256) lstm_scan_b(
    const float* __restrict__ xg, const float* __restrict__ whhf,
    const float* __restrict__ whhb, float* __restrict__ xf, float* __restrict__ xb)
{
    int blk = blockIdx.x;
    int dir = blk >> 6;            // 0..1
    int bp  = blk & 63;            // b-pair index
    int j   = threadIdx.x;         // 0..255

    const float* whh = dir ? whhb : whhf;
    const float4* w0 = (const float4*)(whh + (size_t)(0 * HID_ + j) * HID_);
    const float4* w1 = (const float4*)(whh + (size_t)(1 * HID_ + j) * HID_);
    const float4* w2 = (const float4*)(whh + (size_t)(2 * HID_ + j) * HID_);
    const float4* w3 = (const float4*)(whh + (size_t)(3 * HID_ + j) * HID_);
    float* xo = dir ? xb : xf;

    __shared__ float hs[HID_][2];  // [k][bsub], contiguous 8B per k (ds_read_b64 bcast)
    hs[j][0] = 0.f; hs[j][1] = 0.f;
    float c0 = 0.f, c1 = 0.f;
    __syncthreads();

    for (int t = 0; t < L_; ++t) {
        int slot = dir ? (L_ - 1 - t) : t;
        const float* xbase = xg + (((size_t)dir * L_ + slot) * 64 + bp) * 2048;
        float2 g0 = *(const float2*)(xbase + (0 * HID_ + j) * 2);
        float2 g1 = *(const float2*)(xbase + (1 * HID_ + j) * 2);
        float2 g2 = *(const float2*)(xbase + (2 * HID_ + j) * 2);
        float2 g3 = *(const float2*)(xbase + (3 * HID_ + j) * 2);
        float a00 = g0.x, a01 = g0.y, a10 = g1.x, a11 = g1.y;
        float a20 = g2.x, a21 = g2.y, a30 = g3.x, a31 = g3.y;

        #pragma unroll 4
        for (int k4 = 0; k4 < HID_ / 4; ++k4) {
            float4 v0 = w0[k4], v1 = w1[k4], v2 = w2[k4], v3 = w3[k4];
            float h00 = hs[k4 * 4 + 0][0], h01 = hs[k4 * 4 + 0][1];
            float h10 = hs[k4 * 4 + 1][0], h11 = hs[k4 * 4 + 1][1];
            float h20 = hs[k4 * 4 + 2][0], h21 = hs[k4 * 4 + 2][1];
            float h30 = hs[k4 * 4 + 3][0], h31 = hs[k4 * 4 + 3][1];
            a00 = fmaf(v0.x, h00, a00); a01 = fmaf(v0.x, h01, a01);
            a10 = fmaf(v1.x, h00, a10); a11 = fmaf(v1.x, h01, a11);
            a20 = fmaf(v2.x, h00, a20); a21 = fmaf(v2.x, h01, a21);
            a30 = fmaf(v3.x, h00, a30); a31 = fmaf(v3.x, h01, a31);
            a00 = fmaf(v0.y, h10, a00); a01 = fmaf(v0.y, h11, a01);
            a10 = fmaf(v1.y, h10, a10); a11 = fmaf(v1.y, h11, a11);
            a20 = fmaf(v2.y, h10, a20); a21 = fmaf(v2.y, h11, a21);
            a30 = fmaf(v3.y, h10, a30); a31 = fmaf(v3.y, h11, a31);
            a00 = fmaf(v0.z, h20, a00); a01 = fmaf(v0.z, h21, a01);
            a10 = fmaf(v1.z, h20, a10); a11 = fmaf(v1.z, h21, a11);
            a20 = fmaf(v2.z, h20, a20); a21 = fmaf(v2.z, h21, a21);
            a30 = fmaf(v3.z, h20, a30); a31 = fmaf(v3.z, h21, a31);
            a00 = fmaf(v0.w, h30, a00); a01 = fmaf(v0.w, h31, a01);
            a10 = fmaf(v1.w, h30, a10); a11 = fmaf(v1.w, h31, a11);
            a20 = fmaf(v2.w, h30, a20); a21 = fmaf(v2.w, h31, a21);
            a30 = fmaf(v3.w, h30, a30); a31 = fmaf(v3.w, h31, a31);
        }
        __syncthreads();   // all hs reads of this step complete

        float i0 = 1.f / (1.f + expf(-a00));
        float f0 = 1.f / (1.f + expf(-a10));
        float gg0 = tanhf(a20);
        float o0 = 1.f / (1.f + expf(-a30));
        c0 = f0 * c0 + i0 * gg0;
        float h0 = o0 * tanhf(c0);

        float i1 = 1.f / (1.f + expf(-a01));
        float f1 = 1.f / (1.f + expf(-a11));
        float gg1 = tanhf(a21);
        float o1 = 1.f / (1.f + expf(-a31));
        c1 = f1 * c1 + i1 * gg1;
        float h1 = o1 * tanhf(c1);

        hs[j][0] = h0; hs[j][1] = h1;
        float* xp = xo + ((size_t)slot * HID_ + j) * B_ + bp * 2;
        xp[0] = h0; xp[1] = h1;
        __syncthreads();   // hs writes visible before next step's reads
    }
}

__global__ void x_add(const float* __restrict__ xf, const float* __restrict__ xb,
                      float* __restrict__ x)
{
    int idx = blockIdx.x * 256 + threadIdx.x;   // exactly L_*HID_*B_ threads
    x[idx] = xf[idx] + xb[idx];
}

// ---------------------------------------------------------------------------
// Phase 3: entity features, attention, primary capsules
// ---------------------------------------------------------------------------
__global__ void find_entity(const int* __restrict__ pos1, const int* __restrict__ pos2,
                            int* __restrict__ e)
{
    int b = threadIdx.x;
    int e1 = 0, e2 = 0;
    for (int l = L_ - 1; l >= 0; --l) if (pos1[b * L_ + l] == ENTITY) e1 = l;
    for (int l = L_ - 1; l >= 0; --l) if (pos2[b * L_ + l] == ENTITY) e2 = l;
    e[b] = e1; e[B_ + b] = e2;
}

__global__ void compute_he(const float* __restrict__ x, const int* __restrict__ e,
                           float* __restrict__ he)
{
    int j = blockIdx.x, b = threadIdx.x;
    int e1 = e[b], e2 = e[B_ + b];
    he[j * B_ + b] = x[((size_t)e1 * HID_ + j) * B_ + b] + x[((size_t)e2 * HID_ + j) * B_ + b];
}

__global__ void att_logits(const float* __restrict__ x, const float* __restrict__ he,
                           float* __restrict__ logits)
{
    int l = blockIdx.x, b = threadIdx.x;
    float acc = 0.f;
    for (int j = 0; j < HID_; ++j)
        acc = fmaf(x[((size_t)l * HID_ + j) * B_ + b], he[j * B_ + b], acc);
    logits[l * B_ + b] = acc;
}

__global__ void att_softmax(const float* __restrict__ logits, float* __restrict__ att)
{
    int b = threadIdx.x;
    float m = -1e30f;
    for (int l = 0; l < L_; ++l) m = fmaxf(m, logits[l * B_ + b]);
    float s = 0.f;
    for (int l = 0; l < L_; ++l) s += expf(logits[l * B_ + b] - m);
    float inv = 1.f / s;
    for (int l = 0; l < L_; ++l) att[l * B_ + b] = expf(logits[l * B_ + b] - m) * inv;
}

// primary capsules: u[i][b][c], squashed
__global__ void u_squash(const float* __restrict__ x, float* __restrict__ u)
{
    int i = blockIdx.x, b = threadIdx.x;
    int l = i >> 4, cap = i & 15;
    float vals[16]; float n2 = 0.f;
    #pragma unroll
    for (int c2 = 0; c2 < 16; ++c2) {
        float v = x[((size_t)l * HID_ + cap * 16 + c2) * B_ + b];
        vals[c2] = v; n2 = fmaf(v, v, n2);
    }
    float f = (n2 / (1.f + n2)) / sqrtf(n2 + 1e-9f);
    #pragma unroll
    for (int c2 = 0; c2 < 16; ++c2)
        u[((size_t)i * B_ + b) * 16 + c2] = vals[c2] * f;
}

// ---------------------------------------------------------------------------
// Phase 4: routing
// ---------------------------------------------------------------------------
__global__ void bb_init(const float* __restrict__ br, float* __restrict__ bb)
{
    int idx = blockIdx.x * 256 + threadIdx.x;   // exactly B_*NI*NCLASS threads
    bb[idx] = br[idx % (NI * NCLASS)];
}

__global__ void __launch_bounds__(320) s_pass(
    const float* __restrict__ u, const float* __restrict__ W,
    const float* __restrict__ bb, const float* __restrict__ att,
    float* __restrict__ partial)
{
    int ic = blockIdx.x, bt = blockIdx.y;
    int i0 = ic * 16, b0 = bt * 16;
    __shared__ float C[16][16][20];   // [bl][il][o], padded
    int tid = threadIdx.x;
    if (tid < 256) {
        int bl = tid >> 4, il = tid & 15;
        int b = b0 + bl, i = i0 + il;
        const float* bbp = bb + ((size_t)b * NI + i) * NCLASS;
        float m = bbp[0];
        #pragma unroll
        for (int o = 1; o < NCLASS; ++o) m = fmaxf(m, bbp[o]);
        float s = 0.f; float e[NCLASS];
        #pragma unroll
        for (int o = 0; o < NCLASS; ++o) { e[o] = expf(bbp[o] - m); s += e[o]; }
        float al = att[(i >> 4) * B_ + b] / s;
        #pragma unroll
        for (int o = 0; o < NCLASS; ++o) C[bl][il][o] = e[o] * al;
    }
    __syncthreads();
    if (tid >= OD) return;
    int od = tid, o = od >> 4;
    float acc[16];
    #pragma unroll
    for (int bl = 0; bl < 16; ++bl) acc[bl] = 0.f;
    for (int il = 0; il < 16; ++il) {
        int i = i0 + il;
        const float* wp = W + (size_t)i * 16 * OD + od;
        float w[16];
        #pragma unroll
        for (int c2 = 0; c2 < 16; ++c2) w[c2] = wp[c2 * OD];     // coalesced over od
        const float* up = u + ((size_t)i * B_ + b0) * 16;        // uniform -> s_load
        #pragma unroll
        for (int bl = 0; bl < 16; ++bl) {
            float uh = 0.f;
            #pragma unroll
            for (int c2 = 0; c2 < 16; ++c2) uh = fmaf(up[bl * 16 + c2], w[c2], uh);
            acc[bl] = fmaf(C[bl][il][o], uh, acc[bl]);
        }
    }
    #pragma unroll
    for (int bl = 0; bl < 16; ++bl)
        partial[((size_t)ic * B_ + b0 + bl) * OD + od] = acc[bl];
}

__global__ void s_reduce(const float* __restrict__ partial, float* __restrict__ s)
{
    int idx = blockIdx.x * 256 + threadIdx.x;   // exactly B_*OD threads
    int b = idx / OD, od = idx - b * OD;
    float acc = 0.f;
    for (int ic = 0; ic < 100; ++ic) acc += partial[((size_t)ic * B_ + b) * OD + od];
    s[idx] = acc;
}

__global__ void squash_v(const float* __restrict__ s, float* __restrict__ v,
                         float* __restrict__ out, int write_out)
{
    int idx = blockIdx.x * 256 + threadIdx.x;
    if (idx >= B_ * NCLASS) return;
    const float* sp = s + (size_t)idx * 16;     // b*304 + o*16 == idx*16
    float vals[16]; float n2 = 0.f;
    #pragma unroll
    for (int d = 0; d < 16; ++d) { vals[d] = sp[d]; n2 = fmaf(vals[d], vals[d], n2); }
    float f = (n2 / (1.f + n2)) / sqrtf(n2 + 1e-9f);
    float n2v = 0.f;
    #pragma unroll
    for (int d = 0; d < 16; ++d) {
        float vv = vals[d] * f;
        v[(size_t)idx * 16 + d] = vv;
        n2v = fmaf(vv, vv, n2v);
    }
    if (write_out) out[idx] = sqrtf(n2v + 1e-9f);
}

__global__ void __launch_bounds__(320) bb_pass(
    const float* __restrict__ u, const float* __restrict__ W,
    const float* __restrict__ v, float* __restrict__ bb)
{
    int ic = blockIdx.x, bt = blockIdx.y;
    int i0 = ic * 16, b0 = bt * 16;
    int tid = threadIdx.x;
    if (tid >= OD) return;
    int od = tid, o = od >> 4, d = od & 15;
    float vv[16];
    #pragma unroll
    for (int bl = 0; bl < 16; ++bl) vv[bl] = v[(size_t)(b0 + bl) * OD + od];
    for (int il = 0; il < 16; ++il) {
        int i = i0 + il;
        const float* wp = W + (size_t)i * 16 * OD + od;
        float w[16];
        #pragma unroll
        for (int c2 = 0; c2 < 16; ++c2) w[c2] = wp[c2 * OD];
        const float* up = u + ((size_t)i * B_ + b0) * 16;
        #pragma unroll
        for (int bl = 0; bl < 16; ++bl) {
            float uh = 0.f;
            #pragma unroll
            for (int c2 = 0; c2 < 16; ++c2) uh = fmaf(up[bl * 16 + c2], w[c2], uh);
            float p = uh * vv[bl];
            p += __shfl_xor(p, 1);
            p += __shfl_xor(p, 2);
            p += __shfl_xor(p, 4);
            p += __shfl_xor(p, 8);
            if (d == 0) bb[((size_t)(b0 + bl) * NI + i) * NCLASS + o] += p;
        }
    }
}

// ---------------------------------------------------------------------------
extern "C" void kernel_launch(void* const* d_in, const int* in_sizes, int n_in,
                              void* d_out, int out_size, void* d_ws, size_t ws_size,
                              hipStream_t stream)
{
    (void)in_sizes; (void)n_in; (void)out_size; (void)ws_size;
    const int*   word = (const int*)d_in[0];
    const int*   tag  = (const int*)d_in[1];
    const int*   pos1 = (const int*)d_in[2];
    const int*   pos2 = (const int*)d_in[3];
    const float* we   = (const float*)d_in[4];
    const float* te   = (const float*)d_in[5];
    const float* p1e  = (const float*)d_in[6];
    const float* p2e  = (const float*)d_in[7];
    const float* wihf = (const float*)d_in[8];
    const float* whhf = (const float*)d_in[9];
    const float* bihf = (const float*)d_in[10];
    const float* bhhf = (const float*)d_in[11];
    const float* wihb = (const float*)d_in[12];
    const float* whhb = (const float*)d_in[13];
    const float* bihb = (const float*)d_in[14];
    const float* bhhb = (const float*)d_in[15];
    const float* Wc   = (const float*)d_in[16];
    const float* br   = (const float*)d_in[17];

    float* wsp    = (float*)d_ws;
    float* emb    = wsp;                       //  2,048,000
    float* xg     = wsp + 2048000;             // 26,214,400
    float* xf     = xg + 26214400;             //  3,276,800
    float* xb     = xf + 3276800;              //  3,276,800
    float* he     = xb + 3276800;              //     32,768
    float* logits = he + 32768;                //     12,800
    float* att    = logits + 12800;            //     12,800
    int*   e      = (int*)(att + 12800);       //        256 ints
    // post-scan buffers alias the (dead-after-scan) xg region
    float* x    = xg;                          //  3,276,800
    float* u    = xg + 3276800;                //  3,276,800
    float* bb   = xg + 6553600;                //  3,891,200
    float* part = xg + 10444800;               //  3,891,200
    float* s    = xg + 14336000;               //     38,912
    float* v    = s + 38912;                   //     38,912
    float* out  = (float*)d_out;

    emb_gather<<<8000, 256, 0, stream>>>(word, tag, pos1, pos2, we, te, p1e, p2e, emb);
    gemm_xg<<<dim3(8, 100, 2), 256, 0, stream>>>(emb, wihf, bihf, bhhf, wihb, bihb, bhhb, xg);
    lstm_scan_b<<<128, 256, 0, stream>>>(xg, whhf, whhb, xf, xb);
    x_add<<<12800, 256, 0, stream>>>(xf, xb, x);
    find_entity<<<1, 128, 0, stream>>>(pos1, pos2, e);
    compute_he<<<256, 128, 0, stream>>>(x, e, he);
    att_logits<<<100, 128, 0, stream>>>(x, he, logits);
    att_softmax<<<1, 128, 0, stream>>>(logits, att);
    u_squash<<<1600, 128, 0, stream>>>(x, u);
    bb_init<<<15200, 256, 0, stream>>>(br, bb);
    for (int it = 0; it < 3; ++it) {
        s_pass<<<dim3(100, 8), 320, 0, stream>>>(u, Wc, bb, att, part);
        s_reduce<<<152, 256, 0, stream>>>(part, s);
        squash_v<<<10, 256, 0, stream>>>(s, v, out, (it == 2) ? 1 : 0);
        if (it < 2) bb_pass<<<dim3(100, 8), 320, 0, stream>>>(u, Wc, v, bb);
    }
}